// Round 2
// baseline (310.015 us; speedup 1.0000x reference)
//
#include <hip/hip_runtime.h>
#include <hip/hip_bf16.h>

// Problem constants (fixed by the reference)
#define NN 50000
#define NE 800000
#define NG 64
#define OUTD 768

// fused1 block-range dispatch: [gemm1(mfma) | hist-rank+max stream]
#define G1B ((NN + 63) / 64)        // 782 gemm1 blocks (64 rows/block)
#define HRB 250                     // hist-rank blocks
#define EHR (NE / HRB)              // 3200 edges / block (divisible by 4)

// bf16 helpers: storage is ushort, math is fp32 (RTN-even on store)
__device__ __forceinline__ float bflo(unsigned int u) { return __uint_as_float(u << 16); }
__device__ __forceinline__ float bfhi(unsigned int u) { return __uint_as_float(u & 0xffff0000u); }
__device__ __forceinline__ unsigned short f2bf(float f) {
    unsigned int u = __float_as_uint(f);
    return (unsigned short)((u + 0x7fffu + ((u >> 16) & 1u)) >> 16);
}
__device__ __forceinline__ unsigned int pack2bf(float lo, float hi) {
    return (unsigned int)f2bf(lo) | ((unsigned int)f2bf(hi) << 16);
}

typedef __attribute__((ext_vector_type(8))) short bf16x8;
typedef __attribute__((ext_vector_type(4))) float f32x4;
union FragU { uint4 u4; bf16x8 v; };

// ---------------------------------------------------------------------------
// MFMA GEMM: Y[N rows][Ncols](bf16) = X[rows][K] @ W[K][Ncols], fp32 acc.
// W staged to LDS as bf16 B-fragments (lane n=lane&15, k=quad*8+j).
// A loaded from global per wave (16 rows), fp32 X converted in-register.
// C/D layout: col=lane&15, row=quad*4+reg  [m89-verified].
template <int K, int N>
constexpr int mfma_lds_bytes() { return (K / 32) * (N / 16) * 1024; }

template <int K, int N, typename TX>
__device__ __forceinline__ void mfma_gemm_body(char* smem,
                                               const TX* __restrict__ X,
                                               const float* __restrict__ W,
                                               unsigned short* __restrict__ Y,
                                               int nRows, int bx) {
    constexpr int NCT = N / 16;   // col tiles
    constexpr int KS = K / 32;    // k steps
    const int tid = threadIdx.x;

    // stage W -> LDS bf16 fragments: frag fi=(kc*NCT+ct), entry lane*16B
    for (int q = tid; q < KS * NCT * 64; q += 256) {
        int lane = q & 63;
        int fi = q >> 6;
        int ct = fi % NCT, kc = fi / NCT;
        int col = ct * 16 + (lane & 15);
        int kb = kc * 32 + ((lane >> 4) << 3);
        uint4 w;
        w.x = pack2bf(W[(size_t)(kb + 0) * N + col], W[(size_t)(kb + 1) * N + col]);
        w.y = pack2bf(W[(size_t)(kb + 2) * N + col], W[(size_t)(kb + 3) * N + col]);
        w.z = pack2bf(W[(size_t)(kb + 4) * N + col], W[(size_t)(kb + 5) * N + col]);
        w.w = pack2bf(W[(size_t)(kb + 6) * N + col], W[(size_t)(kb + 7) * N + col]);
        *(uint4*)(smem + (size_t)q * 16) = w;
    }
    __syncthreads();

    const int lane = tid & 63;
    const int wv = tid >> 6;          // wave 0..3 -> 16 rows each
    const int m = lane & 15;
    const int quad = lane >> 4;
    const int row = bx * 64 + wv * 16 + m;
    const bool rowok = row < nRows;
    const TX* xr = X + (size_t)(rowok ? row : 0) * K;

    f32x4 acc[NCT];
#pragma unroll
    for (int ct = 0; ct < NCT; ++ct) acc[ct] = (f32x4){0.f, 0.f, 0.f, 0.f};

#pragma unroll
    for (int kc = 0; kc < KS; ++kc) {
        const int k0 = kc * 32 + quad * 8;
        FragU a;
        if constexpr (sizeof(TX) == 4) {   // fp32 X -> cvt to bf16
            float4 a0 = make_float4(0.f, 0.f, 0.f, 0.f), a1 = a0;
            if (rowok) {
                a0 = *(const float4*)(xr + k0);
                a1 = *(const float4*)(xr + k0 + 4);
            }
            a.u4 = make_uint4(pack2bf(a0.x, a0.y), pack2bf(a0.z, a0.w),
                              pack2bf(a1.x, a1.y), pack2bf(a1.z, a1.w));
        } else {                           // bf16 X direct
            a.u4 = rowok ? *(const uint4*)(xr + k0) : make_uint4(0, 0, 0, 0);
        }
#pragma unroll
        for (int ct = 0; ct < NCT; ++ct) {
            FragU b;
            b.u4 = *(const uint4*)(smem + ((size_t)(kc * NCT + ct) * 64 + lane) * 16);
            acc[ct] = __builtin_amdgcn_mfma_f32_16x16x32_bf16(a.v, b.v, acc[ct], 0, 0, 0);
        }
    }

    const int orowb = bx * 64 + wv * 16 + quad * 4;
#pragma unroll
    for (int ct = 0; ct < NCT; ++ct) {
        int col = ct * 16 + m;
#pragma unroll
        for (int r = 0; r < 4; ++r) {
            int orow = orowb + r;
            if (orow < nRows) Y[(size_t)orow * N + col] = f2bf(acc[ct][r]);
        }
    }
}

template <int K, int N, typename TX>
__global__ __launch_bounds__(256) void mfma_gemm_kernel(const TX* __restrict__ X,
                                                        const float* __restrict__ W,
                                                        unsigned short* __restrict__ Y,
                                                        int nRows) {
    extern __shared__ char smem[];
    mfma_gemm_body<K, N>(smem, X, W, Y, nRows, blockIdx.x);
}

// ---------------------------------------------------------------------------
// fused1: [0,G1B) gemm1 MFMA (x fp32 @ W1 -> bf16);
// [G1B,G1B+HRB): one streaming pass over edges producing
//   rank[e]  = atomicAdd(&gcnt[dst[e]], 1)   (global rank within dst row)
//   dsum[d] += ea[e]                         (float atomic; deg precursor)
//   wmax     = max(ea)                       (block-reduced atomicMax)
// Rank order is run-dependent; aggregation is an fp32 sum so the reordering
// jitter (~1e-7 rel) is far below the bf16-dominated tolerance.
__global__ __launch_bounds__(256) void fused1_kernel(const float* __restrict__ x,
                                                     const float* __restrict__ W1,
                                                     unsigned short* __restrict__ bufA,
                                                     const float* __restrict__ ea,
                                                     unsigned int* wmax,
                                                     const int* __restrict__ dst,
                                                     int* __restrict__ rank,
                                                     int* __restrict__ gcnt,
                                                     float* __restrict__ dsum) {
    extern __shared__ char smem[];
    const int b = blockIdx.x;
    if (b < G1B) {
        mfma_gemm_body<128, 128>(smem, x, W1, bufA, NN, b);
    } else {
        const int b2 = b - G1B;          // 0..HRB-1
        const int base = b2 * EHR;
        const int4* dst4 = (const int4*)(dst + base);
        const float4* ea4 = (const float4*)(ea + base);
        int4* rank4 = (int4*)(rank + base);
        float m = 0.0f;
        for (int g = threadIdx.x; g < EHR / 4; g += 256) {
            const int4 dv = dst4[g];
            const float4 ev = ea4[g];
            int4 r;
            r.x = atomicAdd(&gcnt[dv.x], 1);
            r.y = atomicAdd(&gcnt[dv.y], 1);
            r.z = atomicAdd(&gcnt[dv.z], 1);
            r.w = atomicAdd(&gcnt[dv.w], 1);
            atomicAdd(&dsum[dv.x], ev.x);
            atomicAdd(&dsum[dv.y], ev.y);
            atomicAdd(&dsum[dv.z], ev.z);
            atomicAdd(&dsum[dv.w], ev.w);
            m = fmaxf(fmaxf(m, fmaxf(ev.x, ev.y)), fmaxf(ev.z, ev.w));
            rank4[g] = r;
        }
        // wave max-reduce, then cross-wave via LDS
#pragma unroll
        for (int off = 32; off > 0; off >>= 1) m = fmaxf(m, __shfl_xor(m, off));
        float* red = (float*)smem;
        if ((threadIdx.x & 63) == 0) red[threadIdx.x >> 6] = m;
        __syncthreads();
        if (threadIdx.x == 0) {
            float mm = fmaxf(fmaxf(red[0], red[1]), fmaxf(red[2], red[3]));
            atomicMax(wmax, __float_as_uint(mm));
        }
    }
}

// mid: per-block sums of gcnt (for the rowptr scan) + per-node normalization
// factors from dsum/wmax: nrm = rsqrt(deg)*sqrt(rw), invdeg = 1/deg,
// deg = 1 + rw*sum(ea). Replaces the old comb (segmented prefix) entirely.
__global__ __launch_bounds__(256) void mid_kernel(const int* __restrict__ gcnt,
                                                  const float* __restrict__ dsum,
                                                  const unsigned int* __restrict__ wmax,
                                                  int* __restrict__ blocksum,
                                                  float* __restrict__ nrm,
                                                  float* __restrict__ invdeg) {
    __shared__ int red[256];
    const int n = blockIdx.x * 256 + threadIdx.x;
    int v = 0;
    if (n < NN) {
        v = gcnt[n];
        float rw = 1.0f / __uint_as_float(*wmax);
        float d = fmaf(dsum[n], rw, 1.0f);
        nrm[n] = rsqrtf(d) * sqrtf(rw);
        invdeg[n] = 1.0f / d;
    }
    red[threadIdx.x] = v;
    __syncthreads();
    for (int off = 128; off > 0; off >>= 1) {
        if (threadIdx.x < off) red[threadIdx.x] += red[threadIdx.x + off];
        __syncthreads();
    }
    if (threadIdx.x == 0) blocksum[blockIdx.x] = red[0];
}

// scan3: per-node exclusive scan of gcnt -> rowptr. Every block redundantly
// scans the (<=256-entry) blocksum array for its offset; block 0 writes total.
__global__ __launch_bounds__(256) void scan3_kernel(const int* __restrict__ hist,
                                                    const int* __restrict__ blocksum,
                                                    int* __restrict__ rowptr, int n, int nb) {
    __shared__ int sb[256];
    __shared__ int s[256];
    const int tid = threadIdx.x;
    int bv = (tid < nb) ? blocksum[tid] : 0;
    sb[tid] = bv;
    __syncthreads();
    for (int off = 1; off < 256; off <<= 1) {
        int t = (tid >= off) ? sb[tid - off] : 0;
        __syncthreads();
        sb[tid] += t;
        __syncthreads();
    }
    const int boff = (blockIdx.x > 0) ? sb[blockIdx.x - 1] : 0;
    const int total = sb[nb - 1];

    int i = blockIdx.x * 256 + tid;
    int v = (i < n) ? hist[i] : 0;
    s[tid] = v;
    __syncthreads();
    for (int off = 1; off < 256; off <<= 1) {
        int t = (tid >= off) ? s[tid - off] : 0;
        __syncthreads();
        s[tid] += t;
        __syncthreads();
    }
    if (i < n) rowptr[i] = boff + s[tid] - v;
    if (blockIdx.x == 0 && tid == 0) rowptr[n] = total;
}

// ---------------------------------------------------------------------------
// Atomic-free scatter: pos = rowptr[d] + rank[e]. Writes the fully
// pre-multiplied coefficient nrm[s]*ea*nrm[d] so agg kernels need no gathers
// beyond H (nrm is 200 KB -> L2-resident here).
__global__ void scat_kernel(const int* __restrict__ src, const int* __restrict__ dst,
                            const float* __restrict__ ea,
                            const int* __restrict__ rowptr,
                            const int* __restrict__ rank,
                            const float* __restrict__ nrm,
                            int2* __restrict__ epack, int nE) {
    int e = blockIdx.x * blockDim.x + threadIdx.x;
    if (e >= nE) return;
    int s = e < nE ? src[e] : 0;
    int d = dst[e];
    int pos = rowptr[d] + rank[e];
    float coef = nrm[s] * ea[e] * nrm[d];
    epack[pos] = make_int2(s, __float_as_int(coef));
}

// ---------------------------------------------------------------------------
// Aggregation over bf16 H: out = relu( sum coef*H[src] + invdeg[n]*H[n] + b ).
// One node per wave; EPW = 64/(D/8) edges in flight per iter, 16B (8 bf16)
// per lane, fp32 accumulate, shfl_xor combine, bf16 store. Main loop is
// 4x unrolled (4*EPW edges in flight) for gather MLP.
template <int D>
__global__ __launch_bounds__(256) void agg_kernel(const unsigned short* __restrict__ H,
                                                  const int* __restrict__ rowptr,
                                                  const int2* __restrict__ epack,
                                                  const float* __restrict__ invdeg,
                                                  const float* __restrict__ bias,
                                                  unsigned short* __restrict__ out,
                                                  int nNodes) {
    constexpr int LPE = D / 8;    // lanes per edge (16 / 8 / 4)
    constexpr int EPW = 64 / LPE; // edges per iter  (4 / 8 / 16)
    const int lane = threadIdx.x & 63;
    const int n = (blockIdx.x << 2) | (threadIdx.x >> 6);
    if (n >= nNodes) return;
    const int esub = lane / LPE;
    const int f8 = (lane % LPE) * 8;
    const int s0 = rowptr[n];
    const int cnt = rowptr[n + 1] - s0;
    const int2* ep = epack + s0;

    float a[8] = {};
#define AGG8(c_, u_)                                                            \
    a[0] = fmaf(c_, bflo(u_.x), a[0]); a[1] = fmaf(c_, bfhi(u_.x), a[1]);       \
    a[2] = fmaf(c_, bflo(u_.y), a[2]); a[3] = fmaf(c_, bfhi(u_.y), a[3]);       \
    a[4] = fmaf(c_, bflo(u_.z), a[4]); a[5] = fmaf(c_, bfhi(u_.z), a[5]);       \
    a[6] = fmaf(c_, bflo(u_.w), a[6]); a[7] = fmaf(c_, bfhi(u_.w), a[7]);

    int kb = 0;
    for (; kb + 4 * EPW <= cnt; kb += 4 * EPW) {
        const int2 p0 = ep[kb + 0 * EPW + esub];
        const int2 p1 = ep[kb + 1 * EPW + esub];
        const int2 p2 = ep[kb + 2 * EPW + esub];
        const int2 p3 = ep[kb + 3 * EPW + esub];
        const uint4 u0 = *(const uint4*)(H + (size_t)p0.x * D + f8);
        const uint4 u1 = *(const uint4*)(H + (size_t)p1.x * D + f8);
        const uint4 u2 = *(const uint4*)(H + (size_t)p2.x * D + f8);
        const uint4 u3 = *(const uint4*)(H + (size_t)p3.x * D + f8);
        const float c0 = __int_as_float(p0.y);
        const float c1 = __int_as_float(p1.y);
        const float c2 = __int_as_float(p2.y);
        const float c3 = __int_as_float(p3.y);
        AGG8(c0, u0) AGG8(c1, u1) AGG8(c2, u2) AGG8(c3, u3)
    }
    for (; kb + 2 * EPW <= cnt; kb += 2 * EPW) {
        const int2 p0 = ep[kb + esub];
        const int2 p1 = ep[kb + EPW + esub];
        const uint4 u0 = *(const uint4*)(H + (size_t)p0.x * D + f8);
        const uint4 u1 = *(const uint4*)(H + (size_t)p1.x * D + f8);
        const float c0 = __int_as_float(p0.y);
        const float c1 = __int_as_float(p1.y);
        AGG8(c0, u0) AGG8(c1, u1)
    }
    for (; kb < cnt; kb += EPW) {   // guarded tail
        const int idx = kb + esub;
        const bool ok = idx < cnt;
        const int2 p = ok ? ep[idx] : make_int2(n, 0);
        const uint4 u = *(const uint4*)(H + (size_t)p.x * D + f8);
        const float c = ok ? __int_as_float(p.y) : 0.f;
        AGG8(c, u)
    }
#undef AGG8
#pragma unroll
    for (int off = LPE; off < 64; off <<= 1) {
#pragma unroll
        for (int j = 0; j < 8; ++j) a[j] += __shfl_xor(a[j], off);
    }
    if (esub == 0) {
        const float id = invdeg[n];
        const uint4 un = *(const uint4*)(H + (size_t)n * D + f8);
        const float4 b0 = *(const float4*)(bias + f8);
        const float4 b1 = *(const float4*)(bias + f8 + 4);
        float o[8];
        o[0] = fmaxf(fmaf(id, bflo(un.x), a[0]) + b0.x, 0.f);
        o[1] = fmaxf(fmaf(id, bfhi(un.x), a[1]) + b0.y, 0.f);
        o[2] = fmaxf(fmaf(id, bflo(un.y), a[2]) + b0.z, 0.f);
        o[3] = fmaxf(fmaf(id, bfhi(un.y), a[3]) + b0.w, 0.f);
        o[4] = fmaxf(fmaf(id, bflo(un.z), a[4]) + b1.x, 0.f);
        o[5] = fmaxf(fmaf(id, bfhi(un.z), a[5]) + b1.y, 0.f);
        o[6] = fmaxf(fmaf(id, bflo(un.w), a[6]) + b1.z, 0.f);
        o[7] = fmaxf(fmaf(id, bfhi(un.w), a[7]) + b1.w, 0.f);
        uint4 w;
        w.x = pack2bf(o[0], o[1]);
        w.y = pack2bf(o[2], o[3]);
        w.z = pack2bf(o[4], o[5]);
        w.w = pack2bf(o[6], o[7]);
        *(uint4*)(out + (size_t)n * D + f8) = w;
    }
}

// ---------------------------------------------------------------------------
// Pool + final GEMM fused: batch SORTED -> one 1024-thread block per graph,
// binary search range, mean-pool 32 features (32 nodes/iter), then threads
// 0..767 each compute one output (Wl 98 KB -> L2-resident across 64 blocks).
__global__ __launch_bounds__(1024) void poolfin_kernel(const unsigned short* __restrict__ h,
                                                       const int* __restrict__ batch,
                                                       const float* __restrict__ Wl,
                                                       const float* __restrict__ bl,
                                                       float* __restrict__ out, int n) {
    const int g = blockIdx.x;
    int lo = 0, hi = n;
    while (lo < hi) { int m = (lo + hi) >> 1; if (batch[m] < g) lo = m + 1; else hi = m; }
    const int start = lo;
    lo = start; hi = n;
    while (lo < hi) { int m = (lo + hi) >> 1; if (batch[m] < g + 1) lo = m + 1; else hi = m; }
    const int end = lo;

    __shared__ float part[1024];
    __shared__ float spool[32];
    const int f = threadIdx.x & 31;
    const int r = threadIdx.x >> 5;  // 0..31
    float acc = 0.f;
    for (int i = start + r; i < end; i += 32)
        acc += __uint_as_float((unsigned int)h[(size_t)i * 32 + f] << 16);
    part[threadIdx.x] = acc;
    __syncthreads();
    if (threadIdx.x < 32) {
        float s = 0.f;
#pragma unroll
        for (int q = 0; q < 32; ++q) s += part[q * 32 + f];
        float inv = 1.0f / fmaxf((float)(end - start), 1.0f);
        spool[f] = s * inv;
    }
    __syncthreads();
    if (threadIdx.x < OUTD) {
        const int o = threadIdx.x;
        float a2 = bl[o];
#pragma unroll
        for (int k = 0; k < 32; ++k)
            a2 = fmaf(spool[k], Wl[k * OUTD + o], a2);
        out[(size_t)g * OUTD + o] = a2;
    }
}

// ---------------------------------------------------------------------------
extern "C" void kernel_launch(void* const* d_in, const int* in_sizes, int n_in,
                              void* d_out, int out_size, void* d_ws, size_t ws_size,
                              hipStream_t stream) {
    const float* x = (const float*)d_in[0];
    const int* eidx = (const int*)d_in[1];
    const float* ea = (const float*)d_in[2];
    const int* batch = (const int*)d_in[3];
    const float* W1 = (const float*)d_in[4];
    const float* b1 = (const float*)d_in[5];
    const float* W2 = (const float*)d_in[6];
    const float* b2 = (const float*)d_in[7];
    const float* W3 = (const float*)d_in[8];
    const float* b3 = (const float*)d_in[9];
    const float* Wl = (const float*)d_in[10];
    const float* bl = (const float*)d_in[11];
    const int* src = eidx;
    const int* dst = eidx + NE;

    char* p = (char*)d_ws;
    auto take = [&](size_t bytes) {
        char* r = p;
        p += (bytes + 255) & ~(size_t)255;
        return r;
    };
    float* nrm = (float*)take(NN * 4);
    float* invdeg = (float*)take(NN * 4);
    int* rowptr = (int*)take((NN + 1) * 4);
    int* blocksum = (int*)take(256 * 4);
    int2* epack = (int2*)take((size_t)NE * 8);
    // zero-init region: gcnt | dsum | wmax -> one memset
    char* zbase = take(NN * 4 + NN * 4 + 256);
    int* gcnt = (int*)zbase;                       // doubles as hist
    float* dsum = (float*)(zbase + (size_t)NN * 4);
    unsigned int* wmax = (unsigned int*)(zbase + (size_t)NN * 8);
    unsigned short* bufA = (unsigned short*)take((size_t)NN * 128 * 2);
    unsigned short* bufB = (unsigned short*)take((size_t)NN * 128 * 2);
    // rank aliases bufB (3.2 MB of 12.8 MB): fully consumed by scat_kernel,
    // which completes before agg1 writes bufB (stream-ordered).
    int* rank = (int*)bufB;

    const int nblk = (NN + 255) / 256;   // 196
    const int eblk = (NE + 255) / 256;   // 3125

    hipMemsetAsync(zbase, 0, (size_t)NN * 8 + 4, stream);

    constexpr int LDS1 = mfma_lds_bytes<128, 128>();   // 32768
    // gemm1(mfma) || edge-stream (rank/dsum/max) — independent, co-scheduled.
    // 782+250 = 1032 blocks <= 1280 co-resident (5 blocks/CU at 32 KB LDS):
    // single wave of blocks, no dispatch tail.
    fused1_kernel<<<G1B + HRB, 256, LDS1, stream>>>(x, W1, bufA, ea, wmax,
                                                    dst, rank, gcnt, dsum);
    mid_kernel<<<nblk, 256, 0, stream>>>(gcnt, dsum, wmax, blocksum, nrm, invdeg);
    scan3_kernel<<<nblk, 256, 0, stream>>>(gcnt, blocksum, rowptr, NN, nblk);
    scat_kernel<<<eblk, 256, 0, stream>>>(src, dst, ea, rowptr, rank, nrm, epack, NE);

    // layer 1 aggregate (gemm1 already done inside fused1)
    agg_kernel<128><<<(NN + 3) / 4, 256, 0, stream>>>(bufA, rowptr, epack, invdeg, b1, bufB, NN);
    // layer 2: 128->64 (MFMA)
    mfma_gemm_kernel<128, 64, unsigned short>
        <<<G1B, 256, mfma_lds_bytes<128, 64>(), stream>>>(bufB, W2, bufA, NN);
    agg_kernel<64><<<(NN + 3) / 4, 256, 0, stream>>>(bufA, rowptr, epack, invdeg, b2, bufB, NN);
    // layer 3: 64->32 (MFMA)
    mfma_gemm_kernel<64, 32, unsigned short>
        <<<G1B, 256, mfma_lds_bytes<64, 32>(), stream>>>(bufB, W3, bufA, NN);
    agg_kernel<32><<<(NN + 3) / 4, 256, 0, stream>>>(bufA, rowptr, epack, invdeg, b3, bufB, NN);

    poolfin_kernel<<<NG, 1024, 0, stream>>>(bufB, batch, Wl, bl, (float*)d_out, NN);
}

// Round 3
// 252.313 us; speedup vs baseline: 1.2287x; 1.2287x over previous
//
#include <hip/hip_runtime.h>
#include <hip/hip_bf16.h>

// Problem constants (fixed by the reference)
#define NN 50000
#define NE 800000
#define NG 64
#define OUTD 768

// fused1 block-range dispatch: [gemm1(mfma) | max | hist-rank]
#define G1B ((NN + 63) / 64)        // 782 gemm1 blocks (64 rows/block)
#define MAXB 128                    // max-reduce blocks
#define SSEG 32                     // edge segments
#define TTL 4                       // node tiles (packed u16 counters: 25 KB LDS)
#define ESEG (NE / SSEG)            // 25000 edges / segment
#define NTL (NN / TTL)              // 12500 nodes / tile
#define HRB (SSEG * TTL)            // 128 hist-rank blocks

// bf16 helpers: storage is ushort, math is fp32 (RTN-even on store)
__device__ __forceinline__ float bflo(unsigned int u) { return __uint_as_float(u << 16); }
__device__ __forceinline__ float bfhi(unsigned int u) { return __uint_as_float(u & 0xffff0000u); }
__device__ __forceinline__ unsigned short f2bf(float f) {
    unsigned int u = __float_as_uint(f);
    return (unsigned short)((u + 0x7fffu + ((u >> 16) & 1u)) >> 16);
}
__device__ __forceinline__ unsigned int pack2bf(float lo, float hi) {
    return (unsigned int)f2bf(lo) | ((unsigned int)f2bf(hi) << 16);
}

typedef __attribute__((ext_vector_type(8))) short bf16x8;
typedef __attribute__((ext_vector_type(4))) float f32x4;
union FragU { uint4 u4; bf16x8 v; };

// ---------------------------------------------------------------------------
// MFMA GEMM: Y[N rows][Ncols](bf16) = X[rows][K] @ W[K][Ncols], fp32 acc.
// W staged to LDS as bf16 B-fragments (lane n=lane&15, k=quad*8+j).
// A loaded from global per wave (16 rows), fp32 X converted in-register.
// C/D layout: col=lane&15, row=quad*4+reg  [m89-verified].
template <int K, int N>
constexpr int mfma_lds_bytes() { return (K / 32) * (N / 16) * 1024; }

template <int K, int N, typename TX>
__device__ __forceinline__ void mfma_gemm_body(char* smem,
                                               const TX* __restrict__ X,
                                               const float* __restrict__ W,
                                               unsigned short* __restrict__ Y,
                                               int nRows, int bx) {
    constexpr int NCT = N / 16;   // col tiles
    constexpr int KS = K / 32;    // k steps
    const int tid = threadIdx.x;

    // stage W -> LDS bf16 fragments: frag fi=(kc*NCT+ct), entry lane*16B
    for (int q = tid; q < KS * NCT * 64; q += 256) {
        int lane = q & 63;
        int fi = q >> 6;
        int ct = fi % NCT, kc = fi / NCT;
        int col = ct * 16 + (lane & 15);
        int kb = kc * 32 + ((lane >> 4) << 3);
        uint4 w;
        w.x = pack2bf(W[(size_t)(kb + 0) * N + col], W[(size_t)(kb + 1) * N + col]);
        w.y = pack2bf(W[(size_t)(kb + 2) * N + col], W[(size_t)(kb + 3) * N + col]);
        w.z = pack2bf(W[(size_t)(kb + 4) * N + col], W[(size_t)(kb + 5) * N + col]);
        w.w = pack2bf(W[(size_t)(kb + 6) * N + col], W[(size_t)(kb + 7) * N + col]);
        *(uint4*)(smem + (size_t)q * 16) = w;
    }
    __syncthreads();

    const int lane = tid & 63;
    const int wv = tid >> 6;          // wave 0..3 -> 16 rows each
    const int m = lane & 15;
    const int quad = lane >> 4;
    const int row = bx * 64 + wv * 16 + m;
    const bool rowok = row < nRows;
    const TX* xr = X + (size_t)(rowok ? row : 0) * K;

    f32x4 acc[NCT];
#pragma unroll
    for (int ct = 0; ct < NCT; ++ct) acc[ct] = (f32x4){0.f, 0.f, 0.f, 0.f};

#pragma unroll
    for (int kc = 0; kc < KS; ++kc) {
        const int k0 = kc * 32 + quad * 8;
        FragU a;
        if constexpr (sizeof(TX) == 4) {   // fp32 X -> cvt to bf16
            float4 a0 = make_float4(0.f, 0.f, 0.f, 0.f), a1 = a0;
            if (rowok) {
                a0 = *(const float4*)(xr + k0);
                a1 = *(const float4*)(xr + k0 + 4);
            }
            a.u4 = make_uint4(pack2bf(a0.x, a0.y), pack2bf(a0.z, a0.w),
                              pack2bf(a1.x, a1.y), pack2bf(a1.z, a1.w));
        } else {                           // bf16 X direct
            a.u4 = rowok ? *(const uint4*)(xr + k0) : make_uint4(0, 0, 0, 0);
        }
#pragma unroll
        for (int ct = 0; ct < NCT; ++ct) {
            FragU b;
            b.u4 = *(const uint4*)(smem + ((size_t)(kc * NCT + ct) * 64 + lane) * 16);
            acc[ct] = __builtin_amdgcn_mfma_f32_16x16x32_bf16(a.v, b.v, acc[ct], 0, 0, 0);
        }
    }

    const int orowb = bx * 64 + wv * 16 + quad * 4;
#pragma unroll
    for (int ct = 0; ct < NCT; ++ct) {
        int col = ct * 16 + m;
#pragma unroll
        for (int r = 0; r < 4; ++r) {
            int orow = orowb + r;
            if (orow < nRows) Y[(size_t)orow * N + col] = f2bf(acc[ct][r]);
        }
    }
}

template <int K, int N, typename TX>
__global__ __launch_bounds__(256) void mfma_gemm_kernel(const TX* __restrict__ X,
                                                        const float* __restrict__ W,
                                                        unsigned short* __restrict__ Y,
                                                        int nRows) {
    extern __shared__ char smem[];
    mfma_gemm_body<K, N>(smem, X, W, Y, nRows, blockIdx.x);
}

// ---------------------------------------------------------------------------
// fused1: [0,G1B) gemm1 MFMA (x fp32 @ W1 -> bf16); [G1B,G1B+MAXB) max(ea);
// rest: hist-rank counting via LDS (NO global atomics — round-2's global
// atomicAdd variant measured 91 us vs ~33 us for this scheme).
// HR uses PACKED u16 counters (2 nodes per u32 word): per-(seg,node) count
// <= ESEG=25000 < 65536, so "+ (1<<16)" / "+1" atomicAdd never carries across
// halves. TTL=4 at 25 KB LDS -> 3.2M edge-visits, 128 HR blocks.
__global__ __launch_bounds__(256) void fused1_kernel(const float* __restrict__ x,
                                                     const float* __restrict__ W1,
                                                     unsigned short* __restrict__ bufA,
                                                     const float* __restrict__ ea,
                                                     unsigned int* wmax,
                                                     const int* __restrict__ dst,
                                                     int* __restrict__ rank,
                                                     unsigned short* __restrict__ pcnt) {
    extern __shared__ char smem[];
    const int b = blockIdx.x;
    if (b < G1B) {
        mfma_gemm_body<128, 128>(smem, x, W1, bufA, NN, b);
    } else if (b < G1B + MAXB) {
        float* red = (float*)smem;
        const int bb = b - G1B;
        const float4* ea4 = (const float4*)ea;
        float m = 0.0f;
        for (int i = bb * 256 + threadIdx.x; i < NE / 4; i += MAXB * 256) {
            float4 v = ea4[i];
            m = fmaxf(fmaxf(m, fmaxf(v.x, v.y)), fmaxf(v.z, v.w));
        }
        red[threadIdx.x] = m;
        __syncthreads();
        for (int off = 128; off > 0; off >>= 1) {
            if (threadIdx.x < off)
                red[threadIdx.x] = fmaxf(red[threadIdx.x], red[threadIdx.x + off]);
            __syncthreads();
        }
        if (threadIdx.x == 0) atomicMax(wmax, __float_as_uint(red[0]));
    } else {
        const int b2 = b - G1B - MAXB;   // 0..HRB-1
        const int seg = b2 >> 2;         // TTL == 4
        const int tile = b2 & 3;
        unsigned int* lcnt = (unsigned int*)smem;   // NTL/2 u32 = 25 KB (< 32 KB alloc)
        for (int i = threadIdx.x; i < NTL / 2; i += 256) lcnt[i] = 0;
        __syncthreads();
        const int base = seg * ESEG;
        const int nlo = tile * NTL;
        // int4 loads: 4 edges/thread/iter (ESEG divisible by 4; dst 16B aligned)
        const int4* dst4 = (const int4*)(dst + base);
        for (int g = threadIdx.x; g < ESEG / 4; g += 256) {
            const int4 v = dst4[g];
            const int e0 = base + g * 4;
            const int dd[4] = {v.x, v.y, v.z, v.w};
#pragma unroll
            for (int j = 0; j < 4; ++j) {
                int d = dd[j] - nlo;
                if ((unsigned)d < (unsigned)NTL) {
                    unsigned sh = (unsigned)(d & 1) << 4;
                    unsigned old = atomicAdd(&lcnt[d >> 1], 1u << sh);  // LDS atomic
                    rank[e0 + j] = (int)((old >> sh) & 0xffffu);
                }
            }
        }
        __syncthreads();
        // pcnt row: packed u32 stores (node 2i low half, 2i+1 high half; LE)
        unsigned int* prow32 = (unsigned int*)(pcnt + (size_t)seg * NN + nlo);
        for (int i = threadIdx.x; i < NTL / 2; i += 256) prow32[i] = lcnt[i];
    }
}

// Per-node: exclusive prefix over segments (in place, u16), total -> hist,
// and fused block-reduction of totals -> blocksum.
__global__ __launch_bounds__(256) void comb_kernel(unsigned short* __restrict__ pcnt,
                                                   int* __restrict__ hist,
                                                   int* __restrict__ blocksum) {
    __shared__ int red[256];
    int n = blockIdx.x * 256 + threadIdx.x;
    int run = 0;
    if (n < NN) {
#pragma unroll
        for (int s = 0; s < SSEG; ++s) {
            size_t idx = (size_t)s * NN + n;
            int v = pcnt[idx];
            pcnt[idx] = (unsigned short)run;
            run += v;
        }
        hist[n] = run;
    }
    red[threadIdx.x] = (n < NN) ? run : 0;
    __syncthreads();
    for (int off = 128; off > 0; off >>= 1) {
        if (threadIdx.x < off) red[threadIdx.x] += red[threadIdx.x + off];
        __syncthreads();
    }
    if (threadIdx.x == 0) blocksum[blockIdx.x] = red[0];
}

// scan3 with scan2 folded in: every block redundantly scans the (<=256-entry)
// blocksum array to get its own offset; block 0 writes rowptr[NN] = total.
__global__ __launch_bounds__(256) void scan3_kernel(const int* __restrict__ hist,
                                                    const int* __restrict__ blocksum,
                                                    int* __restrict__ rowptr, int n, int nb) {
    __shared__ int sb[256];
    __shared__ int s[256];
    const int tid = threadIdx.x;
    int bv = (tid < nb) ? blocksum[tid] : 0;
    sb[tid] = bv;
    __syncthreads();
    for (int off = 1; off < 256; off <<= 1) {
        int t = (tid >= off) ? sb[tid - off] : 0;
        __syncthreads();
        sb[tid] += t;
        __syncthreads();
    }
    const int boff = (blockIdx.x > 0) ? sb[blockIdx.x - 1] : 0;
    const int total = sb[nb - 1];

    int i = blockIdx.x * 256 + tid;
    int v = (i < n) ? hist[i] : 0;
    s[tid] = v;
    __syncthreads();
    for (int off = 1; off < 256; off <<= 1) {
        int t = (tid >= off) ? s[tid - off] : 0;
        __syncthreads();
        s[tid] += t;
        __syncthreads();
    }
    if (i < n) rowptr[i] = boff + s[tid] - v;
    if (blockIdx.x == 0 && tid == 0) rowptr[n] = total;
}

// ---------------------------------------------------------------------------
// Atomic-free scatter: pos = rowptr[d] + pcnt[seg][d] + rank[e].
__global__ void scat_kernel(const int* __restrict__ src, const int* __restrict__ dst,
                            const float* __restrict__ ea,
                            const int* __restrict__ rowptr,
                            const unsigned short* __restrict__ pcnt,
                            const int* __restrict__ rank,
                            int2* __restrict__ epack, int nE) {
    int e = blockIdx.x * blockDim.x + threadIdx.x;
    if (e >= nE) return;
    int s = e / ESEG;
    int d = dst[e];
    int pos = rowptr[d] + (int)pcnt[(size_t)s * NN + d] + rank[e];
    epack[pos] = make_int2(src[e], __float_as_int(ea[e]));
}

// deg from contiguous CSR segments (no atomics): deg = 1 + rw * sum(ea).
// nrm = rsqrt(deg) * sqrt(rw): agg computes coef = nrm[src]*ea*nrm[dst]
// on the fly (nrm is 200 KB -> L2-resident gather).
__global__ void deg_kernel(const int2* __restrict__ epack, const int* __restrict__ rowptr,
                           const unsigned int* __restrict__ wmax,
                           float* __restrict__ nrm, float* __restrict__ invdeg, int n) {
    int i = blockIdx.x * blockDim.x + threadIdx.x;
    if (i >= n) return;
    float rw = 1.0f / __uint_as_float(*wmax);
    float srw = sqrtf(rw);
    int s0 = rowptr[i], s1 = rowptr[i + 1];
    float s = 0.f;
    for (int e = s0; e < s1; ++e) s += __int_as_float(epack[e].y);
    float d = fmaf(s, rw, 1.0f);
    nrm[i] = rsqrtf(d) * srw;
    invdeg[i] = 1.0f / d;
}

// ---------------------------------------------------------------------------
// Aggregation over bf16 H: out = relu( sum nrm[s]*ea*nrm[n]*H[s] + invdeg[n]*H[n] + b ).
// One node per wave; EPW = 64/(D/8) edges in flight per iter, 16B (8 bf16)
// per lane, fp32 accumulate, shfl_xor combine, bf16 store. Main loop is
// 4x unrolled (4*EPW edges in flight) for gather MLP in this latency-bound loop.
template <int D>
__global__ __launch_bounds__(256) void agg_kernel(const unsigned short* __restrict__ H,
                                                  const int* __restrict__ rowptr,
                                                  const int2* __restrict__ epack,
                                                  const float* __restrict__ invdeg,
                                                  const float* __restrict__ nrm,
                                                  const float* __restrict__ bias,
                                                  unsigned short* __restrict__ out,
                                                  int nNodes) {
    constexpr int LPE = D / 8;    // lanes per edge (16 / 8 / 4)
    constexpr int EPW = 64 / LPE; // edges per iter  (4 / 8 / 16)
    const int lane = threadIdx.x & 63;
    const int n = (blockIdx.x << 2) | (threadIdx.x >> 6);
    if (n >= nNodes) return;
    const int esub = lane / LPE;
    const int f8 = (lane % LPE) * 8;
    const int s0 = rowptr[n];
    const int cnt = rowptr[n + 1] - s0;
    const int2* ep = epack + s0;
    const float dn = nrm[n];

    float a[8] = {};
#define AGG8(c_, u_)                                                            \
    a[0] = fmaf(c_, bflo(u_.x), a[0]); a[1] = fmaf(c_, bfhi(u_.x), a[1]);       \
    a[2] = fmaf(c_, bflo(u_.y), a[2]); a[3] = fmaf(c_, bfhi(u_.y), a[3]);       \
    a[4] = fmaf(c_, bflo(u_.z), a[4]); a[5] = fmaf(c_, bfhi(u_.z), a[5]);       \
    a[6] = fmaf(c_, bflo(u_.w), a[6]); a[7] = fmaf(c_, bfhi(u_.w), a[7]);

    int kb = 0;
    for (; kb + 4 * EPW <= cnt; kb += 4 * EPW) {
        const int2 p0 = ep[kb + 0 * EPW + esub];
        const int2 p1 = ep[kb + 1 * EPW + esub];
        const int2 p2 = ep[kb + 2 * EPW + esub];
        const int2 p3 = ep[kb + 3 * EPW + esub];
        const uint4 u0 = *(const uint4*)(H + (size_t)p0.x * D + f8);
        const uint4 u1 = *(const uint4*)(H + (size_t)p1.x * D + f8);
        const uint4 u2 = *(const uint4*)(H + (size_t)p2.x * D + f8);
        const uint4 u3 = *(const uint4*)(H + (size_t)p3.x * D + f8);
        const float c0 = nrm[p0.x] * __int_as_float(p0.y) * dn;
        const float c1 = nrm[p1.x] * __int_as_float(p1.y) * dn;
        const float c2 = nrm[p2.x] * __int_as_float(p2.y) * dn;
        const float c3 = nrm[p3.x] * __int_as_float(p3.y) * dn;
        AGG8(c0, u0) AGG8(c1, u1) AGG8(c2, u2) AGG8(c3, u3)
    }
    for (; kb + 2 * EPW <= cnt; kb += 2 * EPW) {
        const int2 p0 = ep[kb + esub];
        const int2 p1 = ep[kb + EPW + esub];
        const uint4 u0 = *(const uint4*)(H + (size_t)p0.x * D + f8);
        const uint4 u1 = *(const uint4*)(H + (size_t)p1.x * D + f8);
        const float c0 = nrm[p0.x] * __int_as_float(p0.y) * dn;
        const float c1 = nrm[p1.x] * __int_as_float(p1.y) * dn;
        AGG8(c0, u0) AGG8(c1, u1)
    }
    for (; kb < cnt; kb += EPW) {   // guarded tail
        const int idx = kb + esub;
        const bool ok = idx < cnt;
        const int2 p = ok ? ep[idx] : make_int2(n, 0);
        const uint4 u = *(const uint4*)(H + (size_t)p.x * D + f8);
        const float c = ok ? nrm[p.x] * __int_as_float(p.y) * dn : 0.f;
        AGG8(c, u)
    }
#undef AGG8
#pragma unroll
    for (int off = LPE; off < 64; off <<= 1) {
#pragma unroll
        for (int j = 0; j < 8; ++j) a[j] += __shfl_xor(a[j], off);
    }
    if (esub == 0) {
        const float id = invdeg[n];
        const uint4 un = *(const uint4*)(H + (size_t)n * D + f8);
        const float4 b0 = *(const float4*)(bias + f8);
        const float4 b1 = *(const float4*)(bias + f8 + 4);
        float o[8];
        o[0] = fmaxf(fmaf(id, bflo(un.x), a[0]) + b0.x, 0.f);
        o[1] = fmaxf(fmaf(id, bfhi(un.x), a[1]) + b0.y, 0.f);
        o[2] = fmaxf(fmaf(id, bflo(un.y), a[2]) + b0.z, 0.f);
        o[3] = fmaxf(fmaf(id, bfhi(un.y), a[3]) + b0.w, 0.f);
        o[4] = fmaxf(fmaf(id, bflo(un.z), a[4]) + b1.x, 0.f);
        o[5] = fmaxf(fmaf(id, bfhi(un.z), a[5]) + b1.y, 0.f);
        o[6] = fmaxf(fmaf(id, bflo(un.w), a[6]) + b1.z, 0.f);
        o[7] = fmaxf(fmaf(id, bfhi(un.w), a[7]) + b1.w, 0.f);
        uint4 w;
        w.x = pack2bf(o[0], o[1]);
        w.y = pack2bf(o[2], o[3]);
        w.z = pack2bf(o[4], o[5]);
        w.w = pack2bf(o[6], o[7]);
        *(uint4*)(out + (size_t)n * D + f8) = w;
    }
}

// ---------------------------------------------------------------------------
// Pool + final GEMM fused: batch SORTED -> one 1024-thread block per graph,
// binary search range, mean-pool 32 features (32 nodes/iter), then threads
// 0..767 each compute one output (Wl 98 KB -> L2-resident across 64 blocks).
__global__ __launch_bounds__(1024) void poolfin_kernel(const unsigned short* __restrict__ h,
                                                       const int* __restrict__ batch,
                                                       const float* __restrict__ Wl,
                                                       const float* __restrict__ bl,
                                                       float* __restrict__ out, int n) {
    const int g = blockIdx.x;
    int lo = 0, hi = n;
    while (lo < hi) { int m = (lo + hi) >> 1; if (batch[m] < g) lo = m + 1; else hi = m; }
    const int start = lo;
    lo = start; hi = n;
    while (lo < hi) { int m = (lo + hi) >> 1; if (batch[m] < g + 1) lo = m + 1; else hi = m; }
    const int end = lo;

    __shared__ float part[1024];
    __shared__ float spool[32];
    const int f = threadIdx.x & 31;
    const int r = threadIdx.x >> 5;  // 0..31
    float acc = 0.f;
    for (int i = start + r; i < end; i += 32)
        acc += __uint_as_float((unsigned int)h[(size_t)i * 32 + f] << 16);
    part[threadIdx.x] = acc;
    __syncthreads();
    if (threadIdx.x < 32) {
        float s = 0.f;
#pragma unroll
        for (int q = 0; q < 32; ++q) s += part[q * 32 + f];
        float inv = 1.0f / fmaxf((float)(end - start), 1.0f);
        spool[f] = s * inv;
    }
    __syncthreads();
    if (threadIdx.x < OUTD) {
        const int o = threadIdx.x;
        float a2 = bl[o];
#pragma unroll
        for (int k = 0; k < 32; ++k)
            a2 = fmaf(spool[k], Wl[k * OUTD + o], a2);
        out[(size_t)g * OUTD + o] = a2;
    }
}

// ---------------------------------------------------------------------------
extern "C" void kernel_launch(void* const* d_in, const int* in_sizes, int n_in,
                              void* d_out, int out_size, void* d_ws, size_t ws_size,
                              hipStream_t stream) {
    const float* x = (const float*)d_in[0];
    const int* eidx = (const int*)d_in[1];
    const float* ea = (const float*)d_in[2];
    const int* batch = (const int*)d_in[3];
    const float* W1 = (const float*)d_in[4];
    const float* b1 = (const float*)d_in[5];
    const float* W2 = (const float*)d_in[6];
    const float* b2 = (const float*)d_in[7];
    const float* W3 = (const float*)d_in[8];
    const float* b3 = (const float*)d_in[9];
    const float* Wl = (const float*)d_in[10];
    const float* bl = (const float*)d_in[11];
    const int* src = eidx;
    const int* dst = eidx + NE;

    char* p = (char*)d_ws;
    auto take = [&](size_t bytes) {
        char* r = p;
        p += (bytes + 255) & ~(size_t)255;
        return r;
    };
    float* nrm = (float*)take(NN * 4);
    float* invdeg = (float*)take(NN * 4);
    int* hist = (int*)take(NN * 4);
    int* rowptr = (int*)take((NN + 1) * 4);
    int* blocksum = (int*)take(256 * 4);
    int2* epack = (int2*)take((size_t)NE * 8);
    unsigned int* wmax = (unsigned int*)take(4);
    unsigned short* bufA = (unsigned short*)take((size_t)NN * 128 * 2);
    unsigned short* bufB = (unsigned short*)take((size_t)NN * 128 * 2);
    // rank & pcnt alias bufB (12.8 MB): both fully consumed by scat_kernel,
    // which completes before agg1 writes bufB (stream-ordered).
    int* rank = (int*)bufB;                                        // 3.2 MB
    unsigned short* pcnt = (unsigned short*)((char*)bufB + (size_t)NE * 4 + 256);  // 3.2 MB

    const int nblk = (NN + 255) / 256;   // 196
    const int eblk = (NE + 255) / 256;   // 3125

    hipMemsetAsync(wmax, 0, 4, stream);

    constexpr int LDS1 = mfma_lds_bytes<128, 128>();   // 32768
    static_assert(LDS1 >= NTL * 2, "HR branch LDS (packed u16 counters) must fit");
    // gemm1(mfma) || max || hist-rank — mutually independent, co-scheduled.
    // 782+128+128 = 1038 blocks <= 1280 co-resident (5 blocks/CU at 32 KB LDS):
    // single wave of blocks, no dispatch tail.
    fused1_kernel<<<G1B + MAXB + HRB, 256, LDS1, stream>>>(x, W1, bufA, ea, wmax,
                                                           dst, rank, pcnt);
    comb_kernel<<<nblk, 256, 0, stream>>>(pcnt, hist, blocksum);
    scan3_kernel<<<nblk, 256, 0, stream>>>(hist, blocksum, rowptr, NN, nblk);
    scat_kernel<<<eblk, 256, 0, stream>>>(src, dst, ea, rowptr, pcnt, rank, epack, NE);
    deg_kernel<<<nblk, 256, 0, stream>>>(epack, rowptr, wmax, nrm, invdeg, NN);

    // layer 1 aggregate (gemm1 already done inside fused1)
    agg_kernel<128><<<(NN + 3) / 4, 256, 0, stream>>>(bufA, rowptr, epack, invdeg, nrm, b1, bufB, NN);
    // layer 2: 128->64 (MFMA)
    mfma_gemm_kernel<128, 64, unsigned short>
        <<<G1B, 256, mfma_lds_bytes<128, 64>(), stream>>>(bufB, W2, bufA, NN);
    agg_kernel<64><<<(NN + 3) / 4, 256, 0, stream>>>(bufA, rowptr, epack, invdeg, nrm, b2, bufB, NN);
    // layer 3: 64->32 (MFMA)
    mfma_gemm_kernel<64, 32, unsigned short>
        <<<G1B, 256, mfma_lds_bytes<64, 32>(), stream>>>(bufB, W3, bufA, NN);
    agg_kernel<32><<<(NN + 3) / 4, 256, 0, stream>>>(bufA, rowptr, epack, invdeg, nrm, b3, bufB, NN);

    poolfin_kernel<<<NG, 1024, 0, stream>>>(bufB, batch, Wl, bl, (float*)d_out, NN);
}